// Round 24
// baseline (105.889 us; speedup 1.0000x reference)
//
#include <hip/hip_runtime.h>
#include <cstdint>
#include <cstddef>

// Problem: B=32, S=2048, D=512, H=512
//   sb[b,h]   = state @ W1[:D]
//   h         = tanh(tanh(sb + input@W1[D:]))   <-- DOUBLE tanh (reference quirk)
//   logit[b,s]= sum_h h * w2[h]  - 1e30*(1-mask)
//   p = softmax over S;  pooled[b,d] = sum_s p*input
// Outputs: pooled (16384 f32) ++ logit (65536 f32)
//
// r24: r23's verified f32a kernel at occupancy-2 geometry. Five schedules all
// pinned k1 at ~84us because 1 block/CU + lockstep barriers serialize LDS-read
// phases against MFMA phases (cycle model matches). BM=BN=128, 256 thr (4 waves
// of 64x64, acc 64 VGPR), LDS 64KB -> 2 blocks/CU: second block's MFMA covers
// the first's stalls (m114 mechanism). All addressing/swizzle/gates are the
// r19/r23 algebra scaled by 1/2; plog -> 4 partials.

#define NEG_BIG 1e30f

typedef __attribute__((ext_vector_type(8))) short short8_t;   // 8 x bf16
typedef __attribute__((ext_vector_type(4))) float f32x4;

__device__ inline unsigned short f2bf(float f){
  union { float f; unsigned int u; } v; v.f = f;
  unsigned int r = v.u + 0x7fffu + ((v.u >> 16) & 1u);   // RNE
  return (unsigned short)(r >> 16);
}
// tanh via 1 - 2/(1+e^{2x}): exp overflow -> inf -> rcp -> 0 -> +1; underflow -> -1.
__device__ inline float tanh_cheap(float x){
  return 1.0f - 2.0f*__builtin_amdgcn_rcpf(1.0f + __expf(2.0f*x));
}

typedef __attribute__((address_space(1))) const unsigned int g_u32;
typedef __attribute__((address_space(3))) unsigned int l_u32;
__device__ inline void gload16(const void* g, void* l){
  __builtin_amdgcn_global_load_lds((g_u32*)g, (l_u32*)l, 16, 0, 0);
}

// ---------------------------------------------------------------- K0: prep (tiny)
__global__ __launch_bounds__(256) void k0_prep(const float* __restrict__ state,
                                               const float* __restrict__ W1,
                                               float* __restrict__ sbp,
                                               unsigned short* __restrict__ w1xt){
  const int bid = blockIdx.x, t = threadIdx.x;
  if (bid < 64) {
    const int k0 = (bid >> 3) * 64, h0 = (bid & 7) * 64;
    __shared__ float tile[64][65];
    const int c = t & 63, r0 = t >> 6;
    #pragma unroll
    for (int i = 0; i < 16; ++i){
      int r = r0 + 4*i;
      tile[r][c] = W1[(size_t)(512 + k0 + r)*512 + h0 + c];
    }
    __syncthreads();
    #pragma unroll
    for (int i = 0; i < 16; ++i){
      int r = r0 + 4*i;
      w1xt[(size_t)(h0 + r)*512 + k0 + c] = f2bf(tile[c][r]);
    }
  } else {
    const int idx = bid - 64;               // 0..255
    const int b = idx >> 3, ds = idx & 7;
    __shared__ float stl[64];
    if (t < 64) stl[t] = state[b*512 + ds*64 + t];
    __syncthreads();
    float acc0 = 0.f, acc1 = 0.f;
    #pragma unroll 8
    for (int i = 0; i < 64; ++i){
      const float w = stl[i];
      acc0 += w * W1[(size_t)(ds*64 + i)*512 + t];
      acc1 += w * W1[(size_t)(ds*64 + i)*512 + t + 256];
    }
    sbp[(size_t)(ds*32 + b)*512 + t]       = acc0;
    sbp[(size_t)(ds*32 + b)*512 + t + 256] = acc1;
  }
}

// ---------------------------------------------------------------- K1: 128x128 GEMM, fp32-A in LDS, 2 blocks/CU
// 256 thr (4 waves 2Mx2N, wave-tile 64x64). A: BK=32 f32 (128B rows, phys=c^(row&7)).
// B: BK=64 bf16 (128B rows, same swizzle; one B-tile = 2 kt). LDS 64KB:
// A 2x16KB @0, B 2x16KB @ushort 16384.
// kt q0: {READ_A frags 0-1, READ_B all; STAGE_A(kt+1) [kt>=1]; STAGE_B(bt+1) [even kt]}
// kt q1: {READ_A frags 2-3; MFMA; GATE}
// GATE (r23 ledger, 4 gloads/stage, A issued before B):
//   even kt (B staged): vmcnt(4) retires A(kt+1), leaves B(bt+1) in flight.
//   odd kt / kt=14: vmcnt(0). kt=15: none.
__global__ __launch_bounds__(256, 2) void k1_gemm_f32a(const float* __restrict__ input,
                                                       const unsigned short* __restrict__ w1xt,
                                                       const float* __restrict__ sbp,
                                                       const float* __restrict__ w2,
                                                       float* __restrict__ plog){
  __shared__ unsigned short lds[32768];   // 64 KB

  const int orig = blockIdx.x;            // 2048 blocks, bijective XCD swizzle (2048%8==0)
  const int xcd = orig & 7, qq = orig >> 3;
  const int mtile = xcd*64 + (qq >> 2);
  const int nt = qq & 3;                  // 4 N-tiles of one mtile adjacent -> A L2 reuse
  const int m0 = mtile*128, n0 = nt*128;
  const int b = m0 >> 11;

  const int t = threadIdx.x;
  const int lane = t & 63, wid = t >> 6;  // 4 waves
  const int wr = wid >> 1, wcn = wid & 1; // wave -> 64x64 quadrant
  const int lr = lane & 15, kg = lane >> 4;
  const int l7 = lr & 7;

  // staging sources (inverse-swizzled per-lane global addr; LDS dest linear)
  const int srow = t >> 3;                               // 0..31
  const int sinv = (t & 7) ^ ((t >> 3) & 7);             // inverse-swizzled 16B chunk
  const float*          gA  = input + (size_t)(m0 + srow)*512 + sinv*4;  // 4 f32/chunk
  const unsigned short* gBp = w1xt  + (size_t)(n0 + srow)*512 + sinv*8;  // 8 bf16/chunk

  f32x4 acc[4][4];
  #pragma unroll
  for (int mi = 0; mi < 4; ++mi)
    #pragma unroll
    for (int ni = 0; ni < 4; ++ni) acc[mi][ni] = (f32x4){0.f,0.f,0.f,0.f};

  short8_t af[2], bf[4];

  // A tile = 128 rows x 32 f32 = 16 KB = 4 gloads (32 rows each)
#define STAGE_A(KT) do{ \
    const float* gs_ = gA + (KT)*32; \
    const unsigned db_ = (unsigned)((((KT)&1)*8192) + wid*512); \
    gload16(gs_,            &lds[db_]); \
    gload16(gs_ + 32*512,   &lds[db_ + 2048]); \
    gload16(gs_ + 64*512,   &lds[db_ + 4096]); \
    gload16(gs_ + 96*512,   &lds[db_ + 6144]); }while(0)

  // B tile = 128 rows x 64 bf16 = 16 KB = 4 gloads (32 rows each); BT = kt>>1
#define STAGE_B(BT) do{ \
    const unsigned short* gs_ = gBp + (BT)*64; \
    const unsigned db_ = 16384u + (unsigned)((((BT)&1)*8192) + wid*512); \
    gload16(gs_,            &lds[db_]); \
    gload16(gs_ + 32*512,   &lds[db_ + 2048]); \
    gload16(gs_ + 64*512,   &lds[db_ + 4096]); \
    gload16(gs_ + 96*512,   &lds[db_ + 6144]); }while(0)

  // read 2 mi fragments (MH half): 4x ds_read_b128 (f32) + 8x cvt_pk -> bf16
#define READ_A_HALF(MH, KT) do{ \
    const unsigned ab_ = (unsigned)(((KT)&1)*8192); \
    _Pragma("unroll") for (int mm = 0; mm < 2; ++mm){ \
      const unsigned r_ = (unsigned)(wr*64 + ((MH)*2+mm)*16 + lr); \
      f32x4 lo_ = *(const f32x4*)&lds[ab_ + r_*64 + (unsigned)(((2*kg    ) ^ l7)*8)]; \
      f32x4 hi_ = *(const f32x4*)&lds[ab_ + r_*64 + (unsigned)(((2*kg + 1) ^ l7)*8)]; \
      union { short8_t s; unsigned u[4]; } pk_; \
      asm("v_cvt_pk_bf16_f32 %0, %1, %2" : "=v"(pk_.u[0]) : "v"(lo_[0]), "v"(lo_[1])); \
      asm("v_cvt_pk_bf16_f32 %0, %1, %2" : "=v"(pk_.u[1]) : "v"(lo_[2]), "v"(lo_[3])); \
      asm("v_cvt_pk_bf16_f32 %0, %1, %2" : "=v"(pk_.u[2]) : "v"(hi_[0]), "v"(hi_[1])); \
      asm("v_cvt_pk_bf16_f32 %0, %1, %2" : "=v"(pk_.u[3]) : "v"(hi_[2]), "v"(hi_[3])); \
      af[mm] = pk_.s; \
    } }while(0)

  // B fragments, all 4 nn: logical chunk = (kt&1)*4 + kg; phys = c ^ l7
#define READ_B_ALL(KT) do{ \
    const unsigned bb_ = 16384u + (unsigned)((((KT)>>1)&1)*8192); \
    const unsigned h4_ = (unsigned)(((KT)&1)*4); \
    _Pragma("unroll") for (int nn = 0; nn < 4; ++nn){ \
      const unsigned rw_ = (unsigned)(wcn*64 + nn*16 + lr); \
      bf[nn] = *(const short8_t*)&lds[bb_ + rw_*64 + (unsigned)(((h4_ + kg) ^ l7)*8)]; } }while(0)

#define MFMA8(MH) do{ \
    __builtin_amdgcn_s_setprio(1); \
    _Pragma("unroll") for (int mm = 0; mm < 2; ++mm) \
      _Pragma("unroll") for (int nn = 0; nn < 4; ++nn) \
        acc[(MH)*2+mm][nn] = __builtin_amdgcn_mfma_f32_16x16x32_bf16(af[mm], bf[nn], acc[(MH)*2+mm][nn], 0,0,0); \
    __builtin_amdgcn_s_setprio(0); }while(0)

  // prologue: A(0) B(0) A(1) = 12 loads; vmcnt(4) -> A(0),B(0) landed, A(1) in flight
  STAGE_A(0); STAGE_B(0); STAGE_A(1);
  asm volatile("s_waitcnt vmcnt(4)" ::: "memory");
  __builtin_amdgcn_s_barrier();

  #pragma unroll
  for (int kt = 0; kt < 16; ++kt){
    // ---- q0: A frags 0-1 + B-all reads, stage next tiles (A first -> older in queue)
    READ_A_HALF(0, kt);
    READ_B_ALL(kt);
    if (kt >= 1 && kt + 1 < 16) STAGE_A(kt + 1);
    if ((kt & 1) == 0 && kt + 2 < 16) STAGE_B((kt >> 1) + 1);
    __builtin_amdgcn_s_barrier();
    asm volatile("s_waitcnt lgkmcnt(0)" ::: "memory");
    __builtin_amdgcn_sched_barrier(0);
    MFMA8(0);
    __builtin_amdgcn_s_barrier();
    // ---- q1: A frags 2-3 (bf held in regs)
    READ_A_HALF(1, kt);
    __builtin_amdgcn_s_barrier();
    asm volatile("s_waitcnt lgkmcnt(0)" ::: "memory");
    __builtin_amdgcn_sched_barrier(0);
    MFMA8(1);
    if (kt < 15){
      if ((kt & 1) == 0 && kt + 2 < 16)
        asm volatile("s_waitcnt vmcnt(4)" ::: "memory");   // retire A(kt+1); B stays in flight
      else
        asm volatile("s_waitcnt vmcnt(0)" ::: "memory");   // odd kt / kt=14: drain all
    }
    __builtin_amdgcn_s_barrier();
  }
#undef STAGE_A
#undef STAGE_B
#undef READ_A_HALF
#undef READ_B_ALL
#undef MFMA8

  // epilogue: tanh(tanh(acc + sb)) * w2, reduce over this block's 128 h-cols
  float w2v[4], sbv[4];
  #pragma unroll
  for (int ni = 0; ni < 4; ++ni){
    const int h = n0 + wcn*64 + ni*16 + lr;
    w2v[ni] = w2[h];
    float s = 0.f;
    #pragma unroll
    for (int ds = 0; ds < 8; ++ds) s += sbp[(size_t)(ds*32 + b)*512 + h];
    sbv[ni] = s;
  }
  float* red = reinterpret_cast<float*>(&lds[0]);   // 256 floats (post-barrier reuse)
  __syncthreads();
  #pragma unroll
  for (int mi = 0; mi < 4; ++mi){
    #pragma unroll
    for (int j = 0; j < 4; ++j){
      float v = 0.f;
      #pragma unroll
      for (int ni = 0; ni < 4; ++ni)
        v += tanh_cheap(tanh_cheap(acc[mi][ni][j] + sbv[ni])) * w2v[ni];
      v += __shfl_xor(v, 1); v += __shfl_xor(v, 2);
      v += __shfl_xor(v, 4); v += __shfl_xor(v, 8);   // sum 16 cols
      if (lr == 0)
        red[wcn*128 + wr*64 + mi*16 + kg*4 + j] = v;  // C/D row=(lane>>4)*4+j
    }
  }
  __syncthreads();
  if (t < 128)
    plog[(size_t)nt*65536 + m0 + t] = red[t] + red[128 + t];
}

// ---------------------------------------------------------------- K2: softmax stats (4 partials)
__global__ __launch_bounds__(256) void k2_softmax(const float* __restrict__ plog,
                                                  const float* __restrict__ mask,
                                                  float* __restrict__ out_logit,
                                                  float* __restrict__ mz){
  const int b = blockIdx.x, t = threadIdx.x;
  float l[8]; float mx = -3.4e38f;
  #pragma unroll
  for (int i = 0; i < 8; ++i){
    const size_t idx = (size_t)b*2048 + t + i*256;
    float v = plog[idx] + plog[65536 + idx] + plog[2*65536 + idx] + plog[3*65536 + idx];
    v -= NEG_BIG * (1.0f - mask[idx]);
    l[i] = v;
    out_logit[idx] = v;
    mx = fmaxf(mx, v);
  }
  __shared__ float red[8];
  const int wid = t >> 6, lane = t & 63;
  #pragma unroll
  for (int off = 1; off < 64; off <<= 1) mx = fmaxf(mx, __shfl_xor(mx, off));
  if (lane == 0) red[wid] = mx;
  __syncthreads();
  mx = fmaxf(fmaxf(red[0], red[1]), fmaxf(red[2], red[3]));
  float zs = 0.f;
  #pragma unroll
  for (int i = 0; i < 8; ++i) zs += __expf(l[i] - mx);
  #pragma unroll
  for (int off = 1; off < 64; off <<= 1) zs += __shfl_xor(zs, off);
  if (lane == 0) red[4 + wid] = zs;
  __syncthreads();
  if (t == 0){ mz[b*2] = mx; mz[b*2+1] = red[4]+red[5]+red[6]+red[7]; }
}

// ---------------------------------------------------------------- K3: pooled partials (fp32, float4/thread)
__global__ __launch_bounds__(256) void k3_pool(const float* __restrict__ input,
                                               const float* __restrict__ logit,
                                               const float* __restrict__ mz,
                                               float* __restrict__ pool){
  const int b = blockIdx.x >> 4, sc = blockIdx.x & 15;
  const int t = threadIdx.x;
  __shared__ float p[128];
  const float m = mz[b*2], invZ = 1.0f / mz[b*2+1];
  if (t < 128) p[t] = __expf(logit[(size_t)b*2048 + sc*128 + t] - m) * invZ;
  __syncthreads();
  const int half = t >> 7, cw = t & 127;
  float a0=0.f,a1=0.f,a2=0.f,a3=0.f;
  const float* base = input + ((size_t)b*2048 + sc*128 + half)*512 + cw*4;
  #pragma unroll 4
  for (int i = 0; i < 64; ++i){
    const float4 v = *reinterpret_cast<const float4*>(base + (size_t)i*1024);
    const float pv = p[half + 2*i];
    a0 += pv*v.x; a1 += pv*v.y; a2 += pv*v.z; a3 += pv*v.w;
  }
  float4 o = {a0,a1,a2,a3};
  *reinterpret_cast<float4*>(pool + (size_t)blockIdx.x*1024 + half*512 + cw*4) = o;
}

// ---------------------------------------------------------------- K4: reduce partials (32 chunks/batch)
__global__ __launch_bounds__(256) void k4_reduce(const float* __restrict__ pool,
                                                 float* __restrict__ out_pooled){
  const int tg = blockIdx.x*256 + threadIdx.x;  // 0..16383
  const int b = tg >> 9, d = tg & 511;
  float s = 0.f;
  #pragma unroll
  for (int c = 0; c < 32; ++c) s += pool[((size_t)b*32 + c)*512 + d];
  out_pooled[tg] = s;
}

// ---------------------------------------------------------------- launch
extern "C" void kernel_launch(void* const* d_in, const int* in_sizes, int n_in,
                              void* d_out, int out_size, void* d_ws, size_t ws_size,
                              hipStream_t stream){
  const float* input = (const float*)d_in[0];
  const float* state = (const float*)d_in[1];
  const float* mask  = (const float*)d_in[2];
  const float* W1    = (const float*)d_in[3];
  const float* w2    = (const float*)d_in[4];

  float* out_pooled = (float*)d_out;
  float* out_logit  = (float*)d_out + 16384;

  char* ws = (char*)d_ws;
  float*          sbp  = (float*)(ws);                   // 512 KB
  unsigned short* w1xt = (unsigned short*)(ws + 524288); // 512 KB
  float*          plog = (float*)(ws + 1048576);         // 1 MB (4 partials)
  float*          mz   = (float*)(ws + 2097152);         // 256 B
  float*          pool = (float*)(ws + 2097408);         // 2 MB
  (void)ws_size; (void)in_sizes; (void)n_in; (void)out_size;

  k0_prep     <<<320,  256, 0, stream>>>(state, W1, sbp, w1xt);
  k1_gemm_f32a<<<2048, 256, 0, stream>>>(input, w1xt, sbp, w2, plog);
  k2_softmax  <<<32,   256, 0, stream>>>(plog, mask, out_logit, mz);
  k3_pool     <<<512,  256, 0, stream>>>(input, out_logit, mz, pool);
  k4_reduce   <<<64,   256, 0, stream>>>(pool, out_pooled);
}

// Round 25
// 96.789 us; speedup vs baseline: 1.0940x; 1.0940x over previous
//
#include <hip/hip_runtime.h>
#include <cstdint>
#include <cstddef>

// Problem: B=32, S=2048, D=512, H=512
//   sb[b,h]   = state @ W1[:D]
//   h         = tanh(tanh(sb + input@W1[D:]))   <-- DOUBLE tanh (reference quirk)
//   logit[b,s]= sum_h h * w2[h]  - 1e30*(1-mask)
//   p = softmax over S;  pooled[b,d] = sum_s p*input
// Outputs: pooled (16384 f32) ++ logit (65536 f32)
//
// FINAL (r25 = r23 verbatim): best verified config, 97.17us.
// k1: 256x256 fp32-A-in-LDS GEMM (BK=32 A / BK=64 B, both 128B-row XOR swizzle),
// 2-phase pipeline with counted vmcnt gates. Post-mortem r24: occupancy-2 variant
// kept the same 8 waves/CU (4wv x 2blk) -> null; six f32a schedules pinned at
// 81-86us (latency/LDS-bound, invariant 4.19M conflicts); fused-A variants all
// spilled (128-VGPR cliff); cvt-pass variants pinned at ~3.2 TB/s RMW wall.

#define NEG_BIG 1e30f

typedef __attribute__((ext_vector_type(8))) short short8_t;   // 8 x bf16
typedef __attribute__((ext_vector_type(4))) float f32x4;

__device__ inline unsigned short f2bf(float f){
  union { float f; unsigned int u; } v; v.f = f;
  unsigned int r = v.u + 0x7fffu + ((v.u >> 16) & 1u);   // RNE
  return (unsigned short)(r >> 16);
}
// tanh via 1 - 2/(1+e^{2x}): exp overflow -> inf -> rcp -> 0 -> +1; underflow -> -1.
__device__ inline float tanh_cheap(float x){
  return 1.0f - 2.0f*__builtin_amdgcn_rcpf(1.0f + __expf(2.0f*x));
}

typedef __attribute__((address_space(1))) const unsigned int g_u32;
typedef __attribute__((address_space(3))) unsigned int l_u32;
__device__ inline void gload16(const void* g, void* l){
  __builtin_amdgcn_global_load_lds((g_u32*)g, (l_u32*)l, 16, 0, 0);
}

// ---------------------------------------------------------------- K0: prep (tiny)
__global__ __launch_bounds__(256) void k0_prep(const float* __restrict__ state,
                                               const float* __restrict__ W1,
                                               float* __restrict__ sbp,
                                               unsigned short* __restrict__ w1xt){
  const int bid = blockIdx.x, t = threadIdx.x;
  if (bid < 64) {
    const int k0 = (bid >> 3) * 64, h0 = (bid & 7) * 64;
    __shared__ float tile[64][65];
    const int c = t & 63, r0 = t >> 6;
    #pragma unroll
    for (int i = 0; i < 16; ++i){
      int r = r0 + 4*i;
      tile[r][c] = W1[(size_t)(512 + k0 + r)*512 + h0 + c];
    }
    __syncthreads();
    #pragma unroll
    for (int i = 0; i < 16; ++i){
      int r = r0 + 4*i;
      w1xt[(size_t)(h0 + r)*512 + k0 + c] = f2bf(tile[c][r]);
    }
  } else {
    const int idx = bid - 64;               // 0..255
    const int b = idx >> 3, ds = idx & 7;
    __shared__ float stl[64];
    if (t < 64) stl[t] = state[b*512 + ds*64 + t];
    __syncthreads();
    float acc0 = 0.f, acc1 = 0.f;
    #pragma unroll 8
    for (int i = 0; i < 64; ++i){
      const float w = stl[i];
      acc0 += w * W1[(size_t)(ds*64 + i)*512 + t];
      acc1 += w * W1[(size_t)(ds*64 + i)*512 + t + 256];
    }
    sbp[(size_t)(ds*32 + b)*512 + t]       = acc0;
    sbp[(size_t)(ds*32 + b)*512 + t + 256] = acc1;
  }
}

// ---------------------------------------------------------------- K1: 256x256 GEMM, fp32-A in LDS, balanced phases
// A: BK=32 f32 (128B rows, phys = c^(row&7)). B: BK=64 bf16 (128B rows, same swizzle).
// LDS 128KB: A 2x32KB @0, B 2x32KB @ushort 32768.
// kt q0: {READ_A lo-half, READ_B all; STAGE_A(kt+1) [kt>=1] then STAGE_B(bt+1) [even kt]}
// kt q1: {READ_A hi-half; MFMA; GATE}
// GATE ledger (in-order queue, A issued before B):
//   even kt with B staged (kt<=12): outstanding A(kt+1)4 then B(bt+1)4 -> vmcnt(4)
//     retires A (needed kt+1), leaves B (needed kt+2; gated next odd kt).
//   otherwise (odd kt / kt=14): vmcnt(0).
__global__ __launch_bounds__(512, 1) void k1_gemm_f32a(const float* __restrict__ input,
                                                       const unsigned short* __restrict__ w1xt,
                                                       const float* __restrict__ sbp,
                                                       const float* __restrict__ w2,
                                                       float* __restrict__ plog){
  __shared__ unsigned short lds[65536];   // 128 KB

  const int orig = blockIdx.x;            // 512 blocks, bijective XCD swizzle (512%8==0)
  const int xcd = orig & 7, qq = orig >> 3;
  const int mtile = xcd*32 + (qq >> 1);
  const int nt = qq & 1;                  // nt 0/1 of same mtile adjacent -> A L2 reuse
  const int m0 = mtile*256, n0 = nt*256;
  const int b = m0 >> 11;

  const int t = threadIdx.x;
  const int lane = t & 63, wid = t >> 6;
  const int wr = wid >> 2, wcn = wid & 3;
  const int lr = lane & 15, kg = lane >> 4;
  const int l7 = lr & 7;

  // staging sources (inverse-swizzled per-lane global addr; LDS dest linear)
  const int srow = t >> 3;                               // 0..63
  const int sinv = (t & 7) ^ ((t >> 3) & 7);             // inverse-swizzled 16B chunk
  const float*          gA  = input + (size_t)(m0 + srow)*512 + sinv*4;  // 4 f32/chunk
  const unsigned short* gBp = w1xt  + (size_t)(n0 + srow)*512 + sinv*8;  // 8 bf16/chunk

  f32x4 acc[8][4];
  #pragma unroll
  for (int mi = 0; mi < 8; ++mi)
    #pragma unroll
    for (int ni = 0; ni < 4; ++ni) acc[mi][ni] = (f32x4){0.f,0.f,0.f,0.f};

  short8_t af[4], bf[4];

  // A tile = 256 rows x 32 f32 = 32 KB = 4 gloads (64 rows each)
#define STAGE_A(KT) do{ \
    const float* gs_ = gA + (KT)*32; \
    const unsigned db_ = (unsigned)((((KT)&1)*16384) + wid*512); \
    gload16(gs_,             &lds[db_]); \
    gload16(gs_ +  64*512,   &lds[db_ + 4096]); \
    gload16(gs_ + 128*512,   &lds[db_ + 8192]); \
    gload16(gs_ + 192*512,   &lds[db_ + 12288]); }while(0)

  // B tile = 256 rows x 64 bf16 = 32 KB = 4 gloads (64 rows each); BT = kt>>1
#define STAGE_B(BT) do{ \
    const unsigned short* gs_ = gBp + (BT)*64; \
    const unsigned db_ = 32768u + (unsigned)((((BT)&1)*16384) + wid*512); \
    gload16(gs_,             &lds[db_]); \
    gload16(gs_ +  64*512,   &lds[db_ + 4096]); \
    gload16(gs_ + 128*512,   &lds[db_ + 8192]); \
    gload16(gs_ + 192*512,   &lds[db_ + 12288]); }while(0)

  // read one mi-half (4 fragments): 8x ds_read_b128 (f32) + 16x cvt_pk -> bf16
#define READ_A_HALF(MH, KT) do{ \
    const unsigned ab_ = (unsigned)(((KT)&1)*16384); \
    _Pragma("unroll") for (int mm = 0; mm < 4; ++mm){ \
      const unsigned r_ = (unsigned)(wr*128 + ((MH)*4+mm)*16 + lr); \
      f32x4 lo_ = *(const f32x4*)&lds[ab_ + r_*64 + (unsigned)(((2*kg    ) ^ l7)*8)]; \
      f32x4 hi_ = *(const f32x4*)&lds[ab_ + r_*64 + (unsigned)(((2*kg + 1) ^ l7)*8)]; \
      union { short8_t s; unsigned u[4]; } pk_; \
      asm("v_cvt_pk_bf16_f32 %0, %1, %2" : "=v"(pk_.u[0]) : "v"(lo_[0]), "v"(lo_[1])); \
      asm("v_cvt_pk_bf16_f32 %0, %1, %2" : "=v"(pk_.u[1]) : "v"(lo_[2]), "v"(lo_[3])); \
      asm("v_cvt_pk_bf16_f32 %0, %1, %2" : "=v"(pk_.u[2]) : "v"(hi_[0]), "v"(hi_[1])); \
      asm("v_cvt_pk_bf16_f32 %0, %1, %2" : "=v"(pk_.u[3]) : "v"(hi_[2]), "v"(hi_[3])); \
      af[mm] = pk_.s; \
    } }while(0)

  // B fragments, all 4 ni: logical chunk = (kt&1)*4 + kg; phys = c ^ l7
#define READ_B_ALL(KT) do{ \
    const unsigned bb_ = 32768u + (unsigned)((((KT)>>1)&1)*16384); \
    const unsigned h4_ = (unsigned)(((KT)&1)*4); \
    _Pragma("unroll") for (int nn = 0; nn < 4; ++nn){ \
      const unsigned rw_ = (unsigned)(wcn*64 + nn*16 + lr); \
      bf[nn] = *(const short8_t*)&lds[bb_ + rw_*64 + (unsigned)(((h4_ + kg) ^ l7)*8)]; } }while(0)

#define MFMA16(MH) do{ \
    __builtin_amdgcn_s_setprio(1); \
    _Pragma("unroll") for (int mm = 0; mm < 4; ++mm) \
      _Pragma("unroll") for (int nn = 0; nn < 4; ++nn) \
        acc[(MH)*4+mm][nn] = __builtin_amdgcn_mfma_f32_16x16x32_bf16(af[mm], bf[nn], acc[(MH)*4+mm][nn], 0,0,0); \
    __builtin_amdgcn_s_setprio(0); }while(0)

  // prologue: A(0) B(0) A(1) = 12 loads; vmcnt(4) -> A(0),B(0) landed, A(1) in flight
  STAGE_A(0); STAGE_B(0); STAGE_A(1);
  asm volatile("s_waitcnt vmcnt(4)" ::: "memory");
  __builtin_amdgcn_s_barrier();

  #pragma unroll
  for (int kt = 0; kt < 16; ++kt){
    // ---- q0: A-lo + B-all reads, stage next tiles (A first -> older in queue)
    READ_A_HALF(0, kt);
    READ_B_ALL(kt);
    if (kt >= 1 && kt + 1 < 16) STAGE_A(kt + 1);
    if ((kt & 1) == 0 && kt + 2 < 16) STAGE_B((kt >> 1) + 1);
    __builtin_amdgcn_s_barrier();
    asm volatile("s_waitcnt lgkmcnt(0)" ::: "memory");
    __builtin_amdgcn_sched_barrier(0);
    MFMA16(0);
    __builtin_amdgcn_s_barrier();
    // ---- q1: A-hi reads (bf held in regs)
    READ_A_HALF(1, kt);
    __builtin_amdgcn_s_barrier();
    asm volatile("s_waitcnt lgkmcnt(0)" ::: "memory");
    __builtin_amdgcn_sched_barrier(0);
    MFMA16(1);
    // ---- counted gate (ledger above)
    if (kt < 15){
      if ((kt & 1) == 0 && kt + 2 < 16)
        asm volatile("s_waitcnt vmcnt(4)" ::: "memory");   // retire A(kt+1); B stays in flight
      else
        asm volatile("s_waitcnt vmcnt(0)" ::: "memory");   // odd kt / kt=14: drain all
    }
    __builtin_amdgcn_s_barrier();
  }
#undef STAGE_A
#undef STAGE_B
#undef READ_A_HALF
#undef READ_B_ALL
#undef MFMA16

  // epilogue: tanh(tanh(acc + sb)) * w2, reduce over this block's 256 h-cols
  float w2v[4], sbv[4];
  #pragma unroll
  for (int ni = 0; ni < 4; ++ni){
    const int h = n0 + wcn*64 + ni*16 + lr;
    w2v[ni] = w2[h];
    float s = 0.f;
    #pragma unroll
    for (int ds = 0; ds < 8; ++ds) s += sbp[(size_t)(ds*32 + b)*512 + h];
    sbv[ni] = s;
  }
  float* red = reinterpret_cast<float*>(&lds[0]);   // 1024 floats (post-barrier reuse)
  #pragma unroll
  for (int mi = 0; mi < 8; ++mi){
    #pragma unroll
    for (int j = 0; j < 4; ++j){
      float v = 0.f;
      #pragma unroll
      for (int ni = 0; ni < 4; ++ni)
        v += tanh_cheap(tanh_cheap(acc[mi][ni][j] + sbv[ni])) * w2v[ni];
      v += __shfl_xor(v, 1); v += __shfl_xor(v, 2);
      v += __shfl_xor(v, 4); v += __shfl_xor(v, 8);   // sum 16 cols
      if (lr == 0)
        red[wcn*256 + wr*128 + mi*16 + kg*4 + j] = v; // C/D row=(lane>>4)*4+j
    }
  }
  __syncthreads();
  if (t < 256)
    plog[(size_t)nt*65536 + m0 + t] = red[t] + red[256+t] + red[512+t] + red[768+t];
}

// ---------------------------------------------------------------- K2: softmax stats (2 partials)
__global__ __launch_bounds__(256) void k2_softmax(const float* __restrict__ plog,
                                                  const float* __restrict__ mask,
                                                  float* __restrict__ out_logit,
                                                  float* __restrict__ mz){
  const int b = blockIdx.x, t = threadIdx.x;
  float l[8]; float mx = -3.4e38f;
  #pragma unroll
  for (int i = 0; i < 8; ++i){
    const size_t idx = (size_t)b*2048 + t + i*256;
    float v = plog[idx] + plog[65536 + idx];
    v -= NEG_BIG * (1.0f - mask[idx]);
    l[i] = v;
    out_logit[idx] = v;
    mx = fmaxf(mx, v);
  }
  __shared__ float red[8];
  const int wid = t >> 6, lane = t & 63;
  #pragma unroll
  for (int off = 1; off < 64; off <<= 1) mx = fmaxf(mx, __shfl_xor(mx, off));
  if (lane == 0) red[wid] = mx;
  __syncthreads();
  mx = fmaxf(fmaxf(red[0], red[1]), fmaxf(red[2], red[3]));
  float zs = 0.f;
  #pragma unroll
  for (int i = 0; i < 8; ++i) zs += __expf(l[i] - mx);
  #pragma unroll
  for (int off = 1; off < 64; off <<= 1) zs += __shfl_xor(zs, off);
  if (lane == 0) red[4 + wid] = zs;
  __syncthreads();
  if (t == 0){ mz[b*2] = mx; mz[b*2+1] = red[4]+red[5]+red[6]+red[7]; }
}

// ---------------------------------------------------------------- K3: pooled partials (fp32, float4/thread)
__global__ __launch_bounds__(256) void k3_pool(const float* __restrict__ input,
                                               const float* __restrict__ logit,
                                               const float* __restrict__ mz,
                                               float* __restrict__ pool){
  const int b = blockIdx.x >> 4, sc = blockIdx.x & 15;
  const int t = threadIdx.x;
  __shared__ float p[128];
  const float m = mz[b*2], invZ = 1.0f / mz[b*2+1];
  if (t < 128) p[t] = __expf(logit[(size_t)b*2048 + sc*128 + t] - m) * invZ;
  __syncthreads();
  const int half = t >> 7, cw = t & 127;
  float a0=0.f,a1=0.f,a2=0.f,a3=0.f;
  const float* base = input + ((size_t)b*2048 + sc*128 + half)*512 + cw*4;
  #pragma unroll 4
  for (int i = 0; i < 64; ++i){
    const float4 v = *reinterpret_cast<const float4*>(base + (size_t)i*1024);
    const float pv = p[half + 2*i];
    a0 += pv*v.x; a1 += pv*v.y; a2 += pv*v.z; a3 += pv*v.w;
  }
  float4 o = {a0,a1,a2,a3};
  *reinterpret_cast<float4*>(pool + (size_t)blockIdx.x*1024 + half*512 + cw*4) = o;
}

// ---------------------------------------------------------------- K4: reduce partials (32 chunks/batch)
__global__ __launch_bounds__(256) void k4_reduce(const float* __restrict__ pool,
                                                 float* __restrict__ out_pooled){
  const int tg = blockIdx.x*256 + threadIdx.x;  // 0..16383
  const int b = tg >> 9, d = tg & 511;
  float s = 0.f;
  #pragma unroll
  for (int c = 0; c < 32; ++c) s += pool[((size_t)b*32 + c)*512 + d];
  out_pooled[tg] = s;
}

// ---------------------------------------------------------------- launch
extern "C" void kernel_launch(void* const* d_in, const int* in_sizes, int n_in,
                              void* d_out, int out_size, void* d_ws, size_t ws_size,
                              hipStream_t stream){
  const float* input = (const float*)d_in[0];
  const float* state = (const float*)d_in[1];
  const float* mask  = (const float*)d_in[2];
  const float* W1    = (const float*)d_in[3];
  const float* w2    = (const float*)d_in[4];

  float* out_pooled = (float*)d_out;
  float* out_logit  = (float*)d_out + 16384;

  char* ws = (char*)d_ws;
  float*          sbp  = (float*)(ws);                   // 512 KB
  unsigned short* w1xt = (unsigned short*)(ws + 524288); // 512 KB
  float*          plog = (float*)(ws + 1048576);         // 512 KB (2 partials)
  float*          mz   = (float*)(ws + 1572864);         // 256 B
  float*          pool = (float*)(ws + 1573120);         // 2 MB
  (void)ws_size; (void)in_sizes; (void)n_in; (void)out_size;

  k0_prep     <<<320, 256, 0, stream>>>(state, W1, sbp, w1xt);
  k1_gemm_f32a<<<512, 512, 0, stream>>>(input, w1xt, sbp, w2, plog);
  k2_softmax  <<<32,  256, 0, stream>>>(plog, mask, out_logit, mz);
  k3_pool     <<<512, 256, 0, stream>>>(input, out_logit, mz, pool);
  k4_reduce   <<<64,  256, 0, stream>>>(pool, out_pooled);
}